// Round 15
// baseline (150.486 us; speedup 1.0000x reference)
//
#include <hip/hip_runtime.h>
#include <math.h>

#define T_ 768
#define TD (T_*64)
#define EPSF 1e-8f

typedef __attribute__((ext_vector_type(8))) short short8;
typedef __attribute__((ext_vector_type(4))) float f32x4;

__device__ __forceinline__ float wave_sum64(float v) {
#pragma unroll
  for (int m = 32; m >= 1; m >>= 1) v += __shfl_xor(v, m, 64);
  return v;
}
__device__ __forceinline__ float sigmoidf_(float x) { return 1.0f / (1.0f + expf(-x)); }

__device__ __forceinline__ unsigned short f2bf(float x) {
  unsigned int u = __float_as_uint(x);
  u += 0x7fffu + ((u >> 16) & 1u);        // RNE
  return (unsigned short)(u >> 16);
}

// acos(x), x in [0,1): sqrt(1-x)*poly3, |err|<=6.7e-5 (A-S 4.4.45)
__device__ __forceinline__ float acos_pos(float x) {
  float s = sqrtf(fmaxf(1.0f - x, 0.0f));
  return s * (1.5707288f + x * (-0.2121144f + x * (0.0742610f + x * (-0.0187293f))));
}

// simplex proj + renorm; feature row f = sqrt(p) (64 bf16).
__device__ __forceinline__ void feat_bf(float v, int row, int lane,
                                        unsigned short* __restrict__ Fb) {
  float sp = fmaxf(v, 0.0f) + log1pf(expf(-fabsf(v)));
  float s = wave_sum64(sp);
  float p1 = fmaxf(sp / (s + EPSF), EPSF);
  float s2 = wave_sum64(p1);
  float p = p1 / (s2 + EPSF);
  Fb[row * 64 + lane] = f2bf(sqrtf(p));
}

// features(bseq) + Xb(bseq, row-major bf16) + fb_w transpose. grid 192x256.
__global__ void __launch_bounds__(256)
phaseA_kernel(const float* __restrict__ bseq, const float* __restrict__ fb_w,
              unsigned short* __restrict__ Fb, unsigned short* __restrict__ Xb,
              float* __restrict__ fbwT) {
  int b = blockIdx.x, tid = threadIdx.x, w = tid >> 6, l = tid & 63;
  int row = b * 4 + w;
  float v = bseq[row * 64 + l];
  feat_bf(v, row, l, Fb);
  Xb[row * 64 + l] = f2bf(v);             // coalesced, one line per row
  if (b < 128) {                          // 128*256 = 4*64*128
    int idx = b * 256 + tid;
    int ll = idx >> 13, r = idx & 8191, d = r >> 7, k = r & 127;
    fbwT[ll * 8192 + k * 64 + d] = fb_w[ll * 8192 + d * 128 + k];
  }
}

// One dispatch per layer. 192 blocks x 1024 thr (16 waves, 4 waves/SIMD);
// block owns rows 4b..4b+3. A-row dup: A tile row lr holds F[i0+(lr&3)].
// F staged linear into LDS; Xb staged WITH TRANSPOSE into LDS [d][row] (stride 776).
// mode 0: plain+feat; 1: pool + gate(l0) + feat(gated); 2: gate+feat; 3: final
__global__ void __launch_bounds__(1024)
layer_k(const unsigned short* __restrict__ Fbi,
        const unsigned short* __restrict__ Xbi,
        int lidx, int mode, int doMlp,
        const float* __restrict__ tbase,     // basin_coords (steps 0-3) / bnew_g (5-7)
        const float* __restrict__ temp_w, const float* __restrict__ temp_b,
        const float* __restrict__ rs_layers,
        const float* __restrict__ xin, float* __restrict__ xout,
        unsigned short* __restrict__ Fbo, unsigned short* __restrict__ Xbo,
        const float* __restrict__ WT, const float* __restrict__ bbias,
        const float* __restrict__ prevX,
        float* __restrict__ gateOut, float* __restrict__ poolPart,
        const float* __restrict__ mlp_pool, const float* __restrict__ basin_coords,
        const float* __restrict__ w1, const float* __restrict__ b1,
        const float* __restrict__ w2, const float* __restrict__ b2,
        const float* __restrict__ uw, const float* __restrict__ ub,
        float* __restrict__ bnew_g,
        const float* __restrict__ bseq, const float* __restrict__ res_scale,
        float* __restrict__ outp) {
  __shared__ __align__(16) float4 stageBuf[6208];       // F: 6144 f4 | X^T padded: 64x97 f4
  __shared__ __align__(16) unsigned short Pl[4][776];   // P numerators bf16
  __shared__ float sums16[16][4];                       // [wave][query]
  __shared__ float pvs[4][4][64];                       // [K-quarter][query][col]
  __shared__ float xs[4][64], ps[4][64];
  __shared__ float part16[16][64];
  __shared__ float pooled[64], h1s[32], aggs[64], bnewS[64];
  int tid = threadIdx.x, w = tid >> 6, l = tid & 63;
  int lr = l & 15, lk = l >> 4;
  int b = blockIdx.x, i0 = b * 4;
  unsigned short* stage_s = reinterpret_cast<unsigned short*>(stageBuf);

  // ---- temperature (and redundant MLP+basin update on step 4) ----
  float temp;
  if (doMlp) {
    {
      float s = 0.f;
      for (int bb2 = w * 12; bb2 < w * 12 + 12; bb2++) s += mlp_pool[bb2 * 64 + l];
      part16[w][l] = s;
    }
    __syncthreads();
    if (tid < 64) {
      float s = 0.f;
#pragma unroll
      for (int q = 0; q < 16; q++) s += part16[q][tid];
      pooled[tid] = s * (1.0f / 768.0f);
    }
    __syncthreads();
    if (tid < 32) {
      float h = b1[tid];
      for (int k = 0; k < 64; k++) h += w1[tid * 64 + k] * pooled[k];
      h1s[tid] = tanhf(h);
    }
    __syncthreads();
    if (tid < 64) {
      float h = b2[tid];
      for (int k = 0; k < 32; k++) h += w2[tid * 32 + k] * h1s[k];
      aggs[tid] = tanhf(h);
    }
    __syncthreads();
    if (tid < 64) {
      float g = ub[tid];
      for (int k = 0; k < 64; k++) g += uw[tid * 128 + k] * basin_coords[k];
      for (int k = 0; k < 64; k++) g += uw[tid * 128 + 64 + k] * aggs[k];
      g = sigmoidf_(g);
      bnewS[tid] = basin_coords[tid] * (1.0f - g) + aggs[tid] * g;
    }
    __syncthreads();
    if (b == 0 && tid < 64) bnew_g[tid] = bnewS[tid];   // publish for steps 5-7
    float v = bnewS[l] * temp_w[lidx * 64 + l];
    v = wave_sum64(v);
    temp = sigmoidf_(v + temp_b[lidx]) + 0.5f;
  } else {
    float v = tbase[l] * temp_w[lidx * 64 + l];
    v = wave_sum64(v);
    temp = sigmoidf_(v + temp_b[lidx]) + 0.5f;
  }
  float inv_t = 1.0f / fmaxf(temp, 1e-6f);

  // ---- stage F (96KB, linear) into LDS: 6 coalesced float4 per thread ----
  {
    const float4* src = reinterpret_cast<const float4*>(Fbi);
    float4 v0 = src[tid],        v1 = src[tid + 1024], v2 = src[tid + 2048];
    float4 v3 = src[tid + 3072], v4 = src[tid + 4096], v5 = src[tid + 5120];
    stageBuf[tid] = v0;        stageBuf[tid + 1024] = v1; stageBuf[tid + 2048] = v2;
    stageBuf[tid + 3072] = v3; stageBuf[tid + 4096] = v4; stageBuf[tid + 5120] = v5;
  }
  __syncthreads();

  // ---- QK Gram (K=64, frags from LDS): wave w: j-tiles 3w..3w+2 ----
  const short8* arow = reinterpret_cast<const short8*>(stage_s + (i0 + (lr & 3)) * 64);
  short8 afr0 = arow[lk], afr1 = arow[4 + lk];

  float sp[4] = {0.f, 0.f, 0.f, 0.f};
#pragma unroll
  for (int jj = 0; jj < 3; jj++) {
    int jt = w * 3 + jj;
    const short8* brow = reinterpret_cast<const short8*>(stage_s + (jt * 16 + lr) * 64);
    f32x4 acc = {0.f, 0.f, 0.f, 0.f};
    acc = __builtin_amdgcn_mfma_f32_16x16x32_bf16(afr0, brow[lk], acc, 0, 0, 0);
    acc = __builtin_amdgcn_mfma_f32_16x16x32_bf16(afr1, brow[4 + lk], acc, 0, 0, 0);
#pragma unroll
    for (int r = 0; r < 4; r++) {
      float inner = fminf(fmaxf(acc[r], 0.0f), 1.0f - 1e-6f);
      float e = expf(-2.0f * acos_pos(inner) * inv_t);   // max logit ~0: no-max safe
      if (lk == 0) Pl[r][jt * 16 + lr] = f2bf(e);
      sp[r] += e;                                        // lk-copies identical
    }
  }
#pragma unroll
  for (int m = 1; m <= 8; m <<= 1)
#pragma unroll
    for (int r = 0; r < 4; r++) sp[r] += __shfl_xor(sp[r], m, 64);
  if (l == 0)
#pragma unroll
    for (int r = 0; r < 4; r++) sums16[w][r] = sp[r];
  __syncthreads();            // QK done: F reads finished, Pl/sums ready

  // ---- stage Xb (96KB row-major) TRANSPOSED into LDS [d][row], stride 776 ----
  {
    const short8* src = reinterpret_cast<const short8*>(Xbi);   // 6144 short8
#pragma unroll
    for (int rnd = 0; rnd < 6; rnd++) {
      int idx = tid + rnd * 1024;
      int row = idx >> 3, d0 = (idx & 7) * 8;
      short8 v = src[idx];
#pragma unroll
      for (int j = 0; j < 8; j++)
        stage_s[(d0 + j) * 776 + row] = v[j];
    }
  }
  __syncthreads();

  // ---- PV (frags from LDS): wave (cg=w&3, kq=w>>2): cols cg*16..+15, K-quarter kq ----
  {
    int cg = w & 3, kq = w >> 2;
    f32x4 pA = {0.f, 0.f, 0.f, 0.f}, pB = {0.f, 0.f, 0.f, 0.f};
    const short8* xtrow =
        reinterpret_cast<const short8*>(stage_s + (cg * 16 + lr) * 776 + kq * 192);
#pragma unroll
    for (int ks = 0; ks < 3; ks++) {
      short8 paA = *reinterpret_cast<const short8*>(&Pl[lr & 3][kq * 192 + ks * 32 + lk * 8]);
      short8 paB = *reinterpret_cast<const short8*>(&Pl[lr & 3][kq * 192 + (ks + 3) * 32 + lk * 8]);
      pA = __builtin_amdgcn_mfma_f32_16x16x32_bf16(paA, xtrow[ks * 4 + lk], pA, 0, 0, 0);
      pB = __builtin_amdgcn_mfma_f32_16x16x32_bf16(paB, xtrow[(ks + 3) * 4 + lk], pB, 0, 0, 0);
    }
    if (lk == 0)
#pragma unroll
      for (int r = 0; r < 4; r++) pvs[kq][r][cg * 16 + lr] = pA[r] + pB[r];
  }
  __syncthreads();

  // ---- normalize + residual: wave-groups all handle row rw=w&3 (idempotent) ----
  int rw = w & 3;
  int row = i0 + rw;
  float stot = 0.f;
#pragma unroll
  for (int q = 0; q < 16; q++) stot += sums16[q][rw];
  float attn = ((pvs[0][rw][l] + pvs[1][rw][l]) + (pvs[2][rw][l] + pvs[3][rw][l])) / stot;
  float xi = xin[row * 64 + l];
  float xo = xi + rs_layers[lidx] * (attn - xi);
  xs[rw][l] = xo;                          // duplicate identical writes: benign
  if (mode == 1 || mode == 2) ps[rw][l] = prevX[row * 64 + l];
  __syncthreads();

  // ---- tails (wave-groups mirror; all writes idempotent, row-major only) ----
  if (mode == 3) {
    outp[row * 64 + l] = xo + 0.01f * res_scale[0] * (xo - bseq[row * 64 + l]);
    return;
  }
  if (mode == 0) {
    xout[row * 64 + l] = xo;
    Xbo[row * 64 + l] = f2bf(xo);
    feat_bf(xo, row, l, Fbo);
    return;
  }
  // gate: a = bbias + [x, prev] . W^T   (WT is (128,64) k-major)
  float a = bbias[l];
#pragma unroll 8
  for (int k = 0; k < 64; k++) a += xs[rw][k] * WT[k * 64 + l];
#pragma unroll 8
  for (int k = 0; k < 64; k++) a += ps[rw][k] * WT[(64 + k) * 64 + l];
  float g = sigmoidf_(a);
  float xn = xo * g + ps[rw][l] * (1.0f - g);
  if (mode == 1) {
    xout[row * 64 + l] = xo;              // ungated pass0-l3 out (prev for pass1 l3)
    gateOut[row * 64 + l] = xn;           // pass1 l0 input
  } else {
    xout[row * 64 + l] = xn;
  }
  Xbo[row * 64 + l] = f2bf(xn);
  feat_bf(xn, row, l, Fbo);
  if (mode == 1 && w == 0)
    poolPart[b * 64 + l] = xs[0][l] + xs[1][l] + xs[2][l] + xs[3][l];
}

extern "C" void kernel_launch(void* const* d_in, const int* in_sizes, int n_in,
                              void* d_out, int out_size, void* d_ws, size_t ws_size,
                              hipStream_t stream) {
  const float* bseq         = (const float*)d_in[0];
  const float* basin_coords = (const float*)d_in[1];
  const float* temp_w       = (const float*)d_in[2];
  const float* temp_b       = (const float*)d_in[3];
  const float* rs_layers    = (const float*)d_in[4];
  const float* fb_w         = (const float*)d_in[5];
  const float* fb_b         = (const float*)d_in[6];
  const float* comp_w1      = (const float*)d_in[7];
  const float* comp_b1      = (const float*)d_in[8];
  const float* comp_w2      = (const float*)d_in[9];
  const float* comp_b2      = (const float*)d_in[10];
  const float* upd_w        = (const float*)d_in[11];
  const float* upd_b        = (const float*)d_in[12];
  const float* res_scale    = (const float*)d_in[13];
  float* out = (float*)d_out;

  float* ws = (float*)d_ws;
  float* xA       = ws;                    // TD
  float* xB       = xA + TD;               // TD
  float* prevb    = xB + TD;               // 4*TD
  float* fbwT     = prevb + 4 * TD;        // 32768
  float* poolPart = fbwT + 32768;          // 192*64
  float* bnew_g   = poolPart + 12288;      // 64 (pad 80)
  unsigned short* Fb0 = (unsigned short*)(bnew_g + 80);  // 768*64 bf16
  unsigned short* Fb1 = Fb0 + 49152;
  unsigned short* Xb0 = Fb1 + 49152;       // 768*64 bf16 row-major
  unsigned short* Xb1 = Xb0 + 49152;

  phaseA_kernel<<<192, 256, 0, stream>>>(bseq, fb_w, Fb0, Xb0, fbwT);

  // ---- pass 0, layer 0 ----
  layer_k<<<192, 1024, 0, stream>>>(
      /*Fbi*/ Fb0, /*Xbi*/ Xb0, /*lidx*/ 0, /*mode*/ 0, /*doMlp*/ 0,
      /*tbase*/ basin_coords, /*temp_w*/ temp_w, /*temp_b*/ temp_b,
      /*rs_layers*/ rs_layers, /*xin*/ bseq, /*xout*/ prevb,
      /*Fbo*/ Fb1, /*Xbo*/ Xb1,
      /*WT*/ nullptr, /*bbias*/ nullptr, /*prevX*/ nullptr,
      /*gateOut*/ nullptr, /*poolPart*/ nullptr,
      /*mlp_pool*/ nullptr, /*basin_coords*/ nullptr,
      /*w1*/ nullptr, /*b1*/ nullptr, /*w2*/ nullptr, /*b2*/ nullptr,
      /*uw*/ nullptr, /*ub*/ nullptr, /*bnew_g*/ nullptr,
      /*bseq*/ nullptr, /*res_scale*/ nullptr, /*outp*/ nullptr);
  // ---- pass 0, layer 1 ----
  layer_k<<<192, 1024, 0, stream>>>(
      /*Fbi*/ Fb1, /*Xbi*/ Xb1, /*lidx*/ 1, /*mode*/ 0, /*doMlp*/ 0,
      /*tbase*/ basin_coords, /*temp_w*/ temp_w, /*temp_b*/ temp_b,
      /*rs_layers*/ rs_layers, /*xin*/ prevb, /*xout*/ prevb + TD,
      /*Fbo*/ Fb0, /*Xbo*/ Xb0,
      /*WT*/ nullptr, /*bbias*/ nullptr, /*prevX*/ nullptr,
      /*gateOut*/ nullptr, /*poolPart*/ nullptr,
      /*mlp_pool*/ nullptr, /*basin_coords*/ nullptr,
      /*w1*/ nullptr, /*b1*/ nullptr, /*w2*/ nullptr, /*b2*/ nullptr,
      /*uw*/ nullptr, /*ub*/ nullptr, /*bnew_g*/ nullptr,
      /*bseq*/ nullptr, /*res_scale*/ nullptr, /*outp*/ nullptr);
  // ---- pass 0, layer 2 ----
  layer_k<<<192, 1024, 0, stream>>>(
      /*Fbi*/ Fb0, /*Xbi*/ Xb0, /*lidx*/ 2, /*mode*/ 0, /*doMlp*/ 0,
      /*tbase*/ basin_coords, /*temp_w*/ temp_w, /*temp_b*/ temp_b,
      /*rs_layers*/ rs_layers, /*xin*/ prevb + TD, /*xout*/ prevb + 2 * TD,
      /*Fbo*/ Fb1, /*Xbo*/ Xb1,
      /*WT*/ nullptr, /*bbias*/ nullptr, /*prevX*/ nullptr,
      /*gateOut*/ nullptr, /*poolPart*/ nullptr,
      /*mlp_pool*/ nullptr, /*basin_coords*/ nullptr,
      /*w1*/ nullptr, /*b1*/ nullptr, /*w2*/ nullptr, /*b2*/ nullptr,
      /*uw*/ nullptr, /*ub*/ nullptr, /*bnew_g*/ nullptr,
      /*bseq*/ nullptr, /*res_scale*/ nullptr, /*outp*/ nullptr);
  // ---- pass 0, layer 3: residual->prevb3; pool; gate(l0)->xA; feat(gated)->Fb0/Xb0 ----
  layer_k<<<192, 1024, 0, stream>>>(
      /*Fbi*/ Fb1, /*Xbi*/ Xb1, /*lidx*/ 3, /*mode*/ 1, /*doMlp*/ 0,
      /*tbase*/ basin_coords, /*temp_w*/ temp_w, /*temp_b*/ temp_b,
      /*rs_layers*/ rs_layers, /*xin*/ prevb + 2 * TD, /*xout*/ prevb + 3 * TD,
      /*Fbo*/ Fb0, /*Xbo*/ Xb0,
      /*WT*/ fbwT, /*bbias*/ fb_b, /*prevX*/ prevb,
      /*gateOut*/ xA, /*poolPart*/ poolPart,
      /*mlp_pool*/ nullptr, /*basin_coords*/ nullptr,
      /*w1*/ nullptr, /*b1*/ nullptr, /*w2*/ nullptr, /*b2*/ nullptr,
      /*uw*/ nullptr, /*ub*/ nullptr, /*bnew_g*/ nullptr,
      /*bseq*/ nullptr, /*res_scale*/ nullptr, /*outp*/ nullptr);
  // ---- pass 1, layer 0 (does MLP/basin update in-prologue) ----
  layer_k<<<192, 1024, 0, stream>>>(
      /*Fbi*/ Fb0, /*Xbi*/ Xb0, /*lidx*/ 0, /*mode*/ 2, /*doMlp*/ 1,
      /*tbase*/ nullptr, /*temp_w*/ temp_w, /*temp_b*/ temp_b,
      /*rs_layers*/ rs_layers, /*xin*/ xA, /*xout*/ xB,
      /*Fbo*/ Fb1, /*Xbo*/ Xb1,
      /*WT*/ fbwT + 8192, /*bbias*/ fb_b + 64, /*prevX*/ prevb + TD,
      /*gateOut*/ nullptr, /*poolPart*/ nullptr,
      /*mlp_pool*/ poolPart, /*basin_coords*/ basin_coords,
      /*w1*/ comp_w1, /*b1*/ comp_b1, /*w2*/ comp_w2, /*b2*/ comp_b2,
      /*uw*/ upd_w, /*ub*/ upd_b, /*bnew_g*/ bnew_g,
      /*bseq*/ nullptr, /*res_scale*/ nullptr, /*outp*/ nullptr);
  // ---- pass 1, layer 1 ----
  layer_k<<<192, 1024, 0, stream>>>(
      /*Fbi*/ Fb1, /*Xbi*/ Xb1, /*lidx*/ 1, /*mode*/ 2, /*doMlp*/ 0,
      /*tbase*/ bnew_g, /*temp_w*/ temp_w, /*temp_b*/ temp_b,
      /*rs_layers*/ rs_layers, /*xin*/ xB, /*xout*/ xA,
      /*Fbo*/ Fb0, /*Xbo*/ Xb0,
      /*WT*/ fbwT + 16384, /*bbias*/ fb_b + 128, /*prevX*/ prevb + 2 * TD,
      /*gateOut*/ nullptr, /*poolPart*/ nullptr,
      /*mlp_pool*/ nullptr, /*basin_coords*/ nullptr,
      /*w1*/ nullptr, /*b1*/ nullptr, /*w2*/ nullptr, /*b2*/ nullptr,
      /*uw*/ nullptr, /*ub*/ nullptr, /*bnew_g*/ nullptr,
      /*bseq*/ nullptr, /*res_scale*/ nullptr, /*outp*/ nullptr);
  // ---- pass 1, layer 2 ----
  layer_k<<<192, 1024, 0, stream>>>(
      /*Fbi*/ Fb0, /*Xbi*/ Xb0, /*lidx*/ 2, /*mode*/ 2, /*doMlp*/ 0,
      /*tbase*/ bnew_g, /*temp_w*/ temp_w, /*temp_b*/ temp_b,
      /*rs_layers*/ rs_layers, /*xin*/ xA, /*xout*/ xB,
      /*Fbo*/ Fb1, /*Xbo*/ Xb1,
      /*WT*/ fbwT + 24576, /*bbias*/ fb_b + 192, /*prevX*/ prevb + 3 * TD,
      /*gateOut*/ nullptr, /*poolPart*/ nullptr,
      /*mlp_pool*/ nullptr, /*basin_coords*/ nullptr,
      /*w1*/ nullptr, /*b1*/ nullptr, /*w2*/ nullptr, /*b2*/ nullptr,
      /*uw*/ nullptr, /*ub*/ nullptr, /*bnew_g*/ nullptr,
      /*bseq*/ nullptr, /*res_scale*/ nullptr, /*outp*/ nullptr);
  // ---- pass 1, layer 3: final output ----
  layer_k<<<192, 1024, 0, stream>>>(
      /*Fbi*/ Fb1, /*Xbi*/ Xb1, /*lidx*/ 3, /*mode*/ 3, /*doMlp*/ 0,
      /*tbase*/ bnew_g, /*temp_w*/ temp_w, /*temp_b*/ temp_b,
      /*rs_layers*/ rs_layers, /*xin*/ xB, /*xout*/ nullptr,
      /*Fbo*/ nullptr, /*Xbo*/ nullptr,
      /*WT*/ nullptr, /*bbias*/ nullptr, /*prevX*/ nullptr,
      /*gateOut*/ nullptr, /*poolPart*/ nullptr,
      /*mlp_pool*/ nullptr, /*basin_coords*/ nullptr,
      /*w1*/ nullptr, /*b1*/ nullptr, /*w2*/ nullptr, /*b2*/ nullptr,
      /*uw*/ nullptr, /*ub*/ nullptr, /*bnew_g*/ nullptr,
      /*bseq*/ bseq, /*res_scale*/ res_scale, /*outp*/ out);
}